// Round 1
// baseline (2769.796 us; speedup 1.0000x reference)
//
#include <hip/hip_runtime.h>
#include <math.h>

#define HW 16384
#define EPSC 1.00001f   // 1 + 1e-5

// ---------------- mean over H*W (per (b,c) plane) ----------------
__global__ void mean_hw_kernel(const float* __restrict__ x, float* __restrict__ out) {
    int blk = blockIdx.x;
    const float4* p4 = (const float4*)(x + (size_t)blk * HW);
    float s = 0.f;
    for (int i = threadIdx.x; i < HW / 4; i += 256) {
        float4 v = p4[i];
        s += v.x + v.y + v.z + v.w;
    }
    for (int off = 32; off > 0; off >>= 1) s += __shfl_down(s, off, 64);
    __shared__ float red[4];
    int lane = threadIdx.x & 63, wid = threadIdx.x >> 6;
    if (lane == 0) red[wid] = s;
    __syncthreads();
    if (threadIdx.x == 0)
        out[blk] = (red[0] + red[1] + red[2] + red[3]) * (1.0f / (float)HW);
}

// ---------------- convva[b,co] = sum_ci conv_w[co,ci]*va[b,ci] ----------------
__global__ void convva_kernel(const float* __restrict__ va, const float* __restrict__ cw,
                              float* __restrict__ out) {
    int t = threadIdx.x;           // 512 = 8*64
    int b = t >> 6, co = t & 63;
    float s = 0.f;
    for (int ci = 0; ci < 128; ci++) s = fmaf(cw[co * 128 + ci], va[b * 128 + ci], s);
    out[t] = s;
}

// ---------------- SE MLP: scale[b,c] = sigmoid(leaky(y@w1^T)@w2^T) ----------------
__global__ void se_mlp_kernel(const float* __restrict__ y, const float* __restrict__ w1,
                              const float* __restrict__ w2, float* __restrict__ scale) {
    __shared__ float t[8][4];
    int tid = threadIdx.x;         // 512
    if (tid < 32) {
        int b = tid >> 2, h = tid & 3;
        float s = 0.f;
        for (int ci = 0; ci < 64; ci++) s = fmaf(y[b * 64 + ci], w1[h * 64 + ci], s);
        t[b][h] = s >= 0.f ? s : 0.01f * s;
    }
    __syncthreads();
    int b = tid >> 6, c = tid & 63;
    float s = 0.f;
    for (int h = 0; h < 4; h++) s = fmaf(t[b][h], w2[c * 4 + h], s);
    scale[b * 64 + c] = 1.0f / (1.0f + __expf(-s));
}

// kse bilinear (align-corners) helper: k table is 25 floats for (b,c)
__device__ __forceinline__ float kse_val(const float* kt, int y, int x) {
    float ys = y * (4.0f / 127.0f);
    int y0 = (int)ys; if (y0 > 4) y0 = 4;
    int y1 = min(y0 + 1, 4);
    float wy = ys - (float)y0;
    float xs = x * (4.0f / 127.0f);
    int x0 = (int)xs; if (x0 > 4) x0 = 4;
    int x1 = min(x0 + 1, 4);
    float wx = xs - (float)x0;
    float r0 = kt[y0 * 5 + x0] * (1.f - wx) + kt[y0 * 5 + x1] * wx;
    float r1 = kt[y1 * 5 + x0] * (1.f - wx) + kt[y1 * 5 + x1] * wx;
    return r0 * (1.f - wy) + r1 * wy;
}

// ---------------- fused triple 1x1 conv over x1 ----------------
// outputs: fuseadd = (conv_w*x1 + conv_w*va + 2*bias)*(1+kse); att0 = sigmoid(fuseadd)
//          f1 = bnlrelu(conv1_w*x1); f2 = bnlrelu(conv2_w*x1)
__global__ __launch_bounds__(256, 2) void fused_1x1_kernel(
    const float* __restrict__ x1, const float* __restrict__ kk,
    const float* __restrict__ cw, const float* __restrict__ c1w, const float* __restrict__ c2w,
    const float* __restrict__ cva, const float* __restrict__ cbias,
    const float* __restrict__ g1, const float* __restrict__ b1,
    const float* __restrict__ g2, const float* __restrict__ b2,
    float* __restrict__ fuseadd, float* __restrict__ att0,
    float* __restrict__ f1, float* __restrict__ f2) {
    __shared__ float xt[128][64];
    __shared__ float wl[3][64][33];
    int b = blockIdx.x >> 8, tile = blockIdx.x & 255;
    int p0 = tile * 64;
    int h = p0 >> 7, w0 = p0 & 127;
    const float* xb = x1 + (size_t)b * 128 * HW + p0;
    for (int e = threadIdx.x; e < 8192; e += 256) {
        int ci = e >> 6, px = e & 63;
        xt[ci][px] = xb[(size_t)ci * HW + px];
    }
    int co = threadIdx.x >> 2, q = threadIdx.x & 3;
    float aw[16], a1[16], a2[16];
#pragma unroll
    for (int j = 0; j < 16; j++) { aw[j] = 0.f; a1[j] = 0.f; a2[j] = 0.f; }
    for (int cc = 0; cc < 128; cc += 32) {
        __syncthreads();
        for (int e = threadIdx.x; e < 2048; e += 256) {
            int c_ = e >> 5, ci = e & 31;
            wl[0][c_][ci] = cw[c_ * 128 + cc + ci];
            wl[1][c_][ci] = c1w[c_ * 128 + cc + ci];
            wl[2][c_][ci] = c2w[c_ * 128 + cc + ci];
        }
        __syncthreads();
        for (int ci = 0; ci < 32; ci++) {
            float w0v = wl[0][co][ci], w1v = wl[1][co][ci], w2v = wl[2][co][ci];
            const float* xr = &xt[cc + ci][q * 16];
#pragma unroll
            for (int j = 0; j < 16; j++) {
                float xv = xr[j];
                aw[j] = fmaf(w0v, xv, aw[j]);
                a1[j] = fmaf(w1v, xv, a1[j]);
                a2[j] = fmaf(w2v, xv, a2[j]);
            }
        }
    }
    float s1v = g1[co] * rsqrtf(EPSC), bb1 = b1[co];
    float s2v = g2[co] * rsqrtf(EPSC), bb2 = b2[co];
    float base = cva[b * 64 + co] + 2.0f * cbias[co];
    const float* kt = kk + (size_t)(b * 64 + co) * 25;
    size_t ob = (size_t)(b * 64 + co) * HW + p0 + q * 16;
#pragma unroll
    for (int j = 0; j < 16; j++) {
        int x = w0 + q * 16 + j;
        float kv = kse_val(kt, h, x);
        float fa = (aw[j] + base) * (1.0f + kv);
        fuseadd[ob + j] = fa;
        att0[ob + j] = 1.0f / (1.0f + __expf(-fa));
        float v1 = fmaf(a1[j], s1v, bb1); f1[ob + j] = v1 >= 0.f ? v1 : 0.01f * v1;
        float v2 = fmaf(a2[j], s2v, bb2); f2[ob + j] = v2 >= 0.f ? v2 : 0.01f * v2;
    }
}

// ---------------- 3x3 conv, 64->64, pad 1. mode: 0=bnlrelu, 1=sigmoid(bnlrelu), 2=bnlrelu*(1+kse)
__global__ __launch_bounds__(256, 2) void conv3x3_kernel(
    const float* __restrict__ x, const float* __restrict__ wgt,
    const float* __restrict__ g, const float* __restrict__ bb,
    const float* __restrict__ kk, float* __restrict__ out, int mode) {
    __shared__ float xl[8][18][20];
    __shared__ float wl[64][73];
    int b = blockIdx.x >> 6, t = blockIdx.x & 63;
    int ty = (t >> 3) * 16, tx = (t & 7) * 16;
    int co = threadIdx.x >> 2, q = threadIdx.x & 3;
    int qy = (q >> 1) * 8, qx = (q & 1) * 8;
    float acc[64];
#pragma unroll
    for (int i = 0; i < 64; i++) acc[i] = 0.f;
    const float* xb = x + (size_t)b * 64 * HW;
    for (int cc = 0; cc < 64; cc += 8) {
        __syncthreads();
        for (int e = threadIdx.x; e < 8 * 18 * 18; e += 256) {
            int ci = e / 324, rem = e % 324, r = rem / 18, c = rem % 18;
            int yy = ty + r - 1, xx = tx + c - 1;
            float v = 0.f;
            if (yy >= 0 && yy < 128 && xx >= 0 && xx < 128)
                v = xb[(size_t)(cc + ci) * HW + yy * 128 + xx];
            xl[ci][r][c] = v;
        }
        for (int e = threadIdx.x; e < 64 * 72; e += 256) {
            int c_ = e / 72, rem = e % 72;
            wl[c_][rem] = wgt[c_ * 576 + cc * 9 + rem];
        }
        __syncthreads();
        for (int ci = 0; ci < 8; ci++) {
            float w[9];
#pragma unroll
            for (int i = 0; i < 9; i++) w[i] = wl[co][ci * 9 + i];
#pragma unroll
            for (int yi = 0; yi < 10; yi++) {
                float r[10];
#pragma unroll
                for (int c = 0; c < 10; c++) r[c] = xl[ci][qy + yi][qx + c];
#pragma unroll
                for (int ky = 0; ky < 3; ky++) {
                    int yo = yi - ky;
                    if (yo >= 0 && yo < 8) {
#pragma unroll
                        for (int xo = 0; xo < 8; xo++) {
                            float s = acc[yo * 8 + xo];
                            s = fmaf(w[ky * 3 + 0], r[xo + 0], s);
                            s = fmaf(w[ky * 3 + 1], r[xo + 1], s);
                            s = fmaf(w[ky * 3 + 2], r[xo + 2], s);
                            acc[yo * 8 + xo] = s;
                        }
                    }
                }
            }
        }
    }
    float sg = g[co] * rsqrtf(EPSC), sb = bb[co];
    size_t ob = (size_t)(b * 64 + co) * HW;
    const float* kt = kk + (size_t)(b * 64 + co) * 25;
#pragma unroll
    for (int yo = 0; yo < 8; yo++) {
        int y = ty + qy + yo;
#pragma unroll
        for (int xo = 0; xo < 8; xo++) {
            int x = tx + qx + xo;
            float v = fmaf(acc[yo * 8 + xo], sg, sb);
            v = v >= 0.f ? v : 0.01f * v;
            if (mode == 1) v = 1.0f / (1.0f + __expf(-v));
            else if (mode == 2) v *= (1.0f + kse_val(kt, y, x));
            out[ob + y * 128 + x] = v;
        }
    }
}

// ---------------- 5x5 conv, 64->64, pad 2, bnlrelu epilogue ----------------
__global__ __launch_bounds__(256, 2) void conv5x5_kernel(
    const float* __restrict__ x, const float* __restrict__ wgt,
    const float* __restrict__ g, const float* __restrict__ bb,
    float* __restrict__ out) {
    __shared__ float xl[4][20][22];
    __shared__ float wl[64][101];
    int b = blockIdx.x >> 6, t = blockIdx.x & 63;
    int ty = (t >> 3) * 16, tx = (t & 7) * 16;
    int co = threadIdx.x >> 2, q = threadIdx.x & 3;
    int qy = (q >> 1) * 8, qx = (q & 1) * 8;
    float acc[64];
#pragma unroll
    for (int i = 0; i < 64; i++) acc[i] = 0.f;
    const float* xb = x + (size_t)b * 64 * HW;
    for (int cc = 0; cc < 64; cc += 4) {
        __syncthreads();
        for (int e = threadIdx.x; e < 4 * 20 * 20; e += 256) {
            int ci = e / 400, rem = e % 400, r = rem / 20, c = rem % 20;
            int yy = ty + r - 2, xx = tx + c - 2;
            float v = 0.f;
            if (yy >= 0 && yy < 128 && xx >= 0 && xx < 128)
                v = xb[(size_t)(cc + ci) * HW + yy * 128 + xx];
            xl[ci][r][c] = v;
        }
        for (int e = threadIdx.x; e < 64 * 100; e += 256) {
            int c_ = e / 100, rem = e % 100;
            wl[c_][rem] = wgt[c_ * 1600 + cc * 25 + rem];
        }
        __syncthreads();
        for (int ci = 0; ci < 4; ci++) {
            float w[25];
#pragma unroll
            for (int i = 0; i < 25; i++) w[i] = wl[co][ci * 25 + i];
#pragma unroll
            for (int yi = 0; yi < 12; yi++) {
                float r[12];
#pragma unroll
                for (int c = 0; c < 12; c++) r[c] = xl[ci][qy + yi][qx + c];
#pragma unroll
                for (int ky = 0; ky < 5; ky++) {
                    int yo = yi - ky;
                    if (yo >= 0 && yo < 8) {
#pragma unroll
                        for (int xo = 0; xo < 8; xo++) {
                            float s = acc[yo * 8 + xo];
                            s = fmaf(w[ky * 5 + 0], r[xo + 0], s);
                            s = fmaf(w[ky * 5 + 1], r[xo + 1], s);
                            s = fmaf(w[ky * 5 + 2], r[xo + 2], s);
                            s = fmaf(w[ky * 5 + 3], r[xo + 3], s);
                            s = fmaf(w[ky * 5 + 4], r[xo + 4], s);
                            acc[yo * 8 + xo] = s;
                        }
                    }
                }
            }
        }
    }
    float sg = g[co] * rsqrtf(EPSC), sb = bb[co];
    size_t ob = (size_t)(b * 64 + co) * HW;
#pragma unroll
    for (int yo = 0; yo < 8; yo++) {
        int y = ty + qy + yo;
#pragma unroll
        for (int xo = 0; xo < 8; xo++) {
            float v = fmaf(acc[yo * 8 + xo], sg, sb);
            v = v >= 0.f ? v : 0.01f * v;
            out[ob + y * 128 + (tx + qx + xo)] = v;
        }
    }
}

// ---------------- dynamic multi-dilation depthwise 5x5 (d=1,2,3) + (1+kse), b0 override ----------------
__global__ __launch_bounds__(256) void dyndil_kernel(const float* __restrict__ f2,
                                                     const float* __restrict__ kk,
                                                     float* __restrict__ out) {
    int b = blockIdx.x >> 9, c = (blockIdx.x >> 3) & 63, rg = blockIdx.x & 7;
    int r = threadIdx.x >> 4, x0 = (threadIdx.x & 15) * 8;
    int y = rg * 16 + r;
    const float* xp = f2 + (size_t)(b * 64 + c) * HW;
    const float* kt = kk + (size_t)(b * 64 + c) * 25;
    float acc[8];
#pragma unroll
    for (int e = 0; e < 8; e++) acc[e] = 0.f;
    if (b != 0) {
        float kw[25];
#pragma unroll
        for (int i = 0; i < 25; i++) kw[i] = kt[i];
        for (int d = 1; d <= 3; d++) {
            for (int i = 0; i < 5; i++) {
                int yy = y + (i - 2) * d;
                if (yy >= 0 && yy < 128) {
                    const float* row = xp + yy * 128;
#pragma unroll
                    for (int j = 0; j < 5; j++) {
                        int off = (j - 2) * d;
                        float w = kw[i * 5 + j];
#pragma unroll
                        for (int e = 0; e < 8; e++) {
                            int xx = x0 + e + off;
                            float v = (xx >= 0 && xx < 128) ? row[xx] : 0.f;
                            acc[e] = fmaf(w, v, acc[e]);
                        }
                    }
                }
            }
        }
    } else {
#pragma unroll
        for (int e = 0; e < 8; e++) acc[e] = xp[y * 128 + x0 + e];
    }
    size_t ob = (size_t)(b * 64 + c) * HW + y * 128 + x0;
#pragma unroll
    for (int e = 0; e < 8; e++)
        out[ob + e] = acc[e] * (1.0f + kse_val(kt, y, x0 + e));
}

// ---------------- 1x1 conv over concat([xa,xb]) (128 -> 64) + bnlrelu ----------------
__global__ __launch_bounds__(256, 2) void conv0a_kernel(
    const float* __restrict__ xa, const float* __restrict__ xb2,
    const float* __restrict__ wgt, const float* __restrict__ g, const float* __restrict__ bb,
    float* __restrict__ out) {
    __shared__ float xt[128][64];
    __shared__ float wl[64][33];
    int b = blockIdx.x >> 8, tile = blockIdx.x & 255;
    int p0 = tile * 64;
    const float* pa = xa + (size_t)b * 64 * HW + p0;
    const float* pb = xb2 + (size_t)b * 64 * HW + p0;
    for (int e = threadIdx.x; e < 4096; e += 256) {
        int ci = e >> 6, px = e & 63;
        xt[ci][px] = pa[(size_t)ci * HW + px];
        xt[64 + ci][px] = pb[(size_t)ci * HW + px];
    }
    int co = threadIdx.x >> 2, q = threadIdx.x & 3;
    float acc[16];
#pragma unroll
    for (int j = 0; j < 16; j++) acc[j] = 0.f;
    for (int cc = 0; cc < 128; cc += 32) {
        __syncthreads();
        for (int e = threadIdx.x; e < 2048; e += 256) {
            int c_ = e >> 5, ci = e & 31;
            wl[c_][ci] = wgt[c_ * 128 + cc + ci];
        }
        __syncthreads();
        for (int ci = 0; ci < 32; ci++) {
            float w = wl[co][ci];
            const float* xr = &xt[cc + ci][q * 16];
#pragma unroll
            for (int j = 0; j < 16; j++) acc[j] = fmaf(w, xr[j], acc[j]);
        }
    }
    float sg = g[co] * rsqrtf(EPSC), sb = bb[co];
    size_t ob = (size_t)(b * 64 + co) * HW + p0 + q * 16;
#pragma unroll
    for (int j = 0; j < 16; j++) {
        float v = fmaf(acc[j], sg, sb);
        out[ob + j] = v >= 0.f ? v : 0.01f * v;
    }
}

// ---------------- elementwise ----------------
__global__ void mul3_kernel(const float* __restrict__ a, const float* __restrict__ b,
                            const float* __restrict__ c, float* __restrict__ o) {
    size_t i = ((size_t)blockIdx.x * 256 + threadIdx.x);
    float4 va = ((const float4*)a)[i], vb = ((const float4*)b)[i], vc = ((const float4*)c)[i];
    float4 r;
    r.x = va.x * vb.x * vc.x; r.y = va.y * vb.y * vc.y;
    r.z = va.z * vb.z * vc.z; r.w = va.w * vb.w * vc.w;
    ((float4*)o)[i] = r;
}

__global__ void add3_kernel(const float* __restrict__ a, const float* __restrict__ b,
                            const float* __restrict__ c, float* __restrict__ o) {
    size_t i = ((size_t)blockIdx.x * 256 + threadIdx.x);
    float4 va = ((const float4*)a)[i], vb = ((const float4*)b)[i], vc = ((const float4*)c)[i];
    float4 r;
    r.x = va.x + vb.x + vc.x; r.y = va.y + vb.y + vc.y;
    r.z = va.z + vb.z + vc.z; r.w = va.w + vb.w + vc.w;
    ((float4*)o)[i] = r;
}

__global__ void final_kernel(const float* __restrict__ att0, const float* __restrict__ scale,
                             const float* __restrict__ outb, const float* __restrict__ a1,
                             float* __restrict__ o) {
    size_t i = ((size_t)blockIdx.x * 256 + threadIdx.x);
    int bc = (int)((i * 4) >> 14);
    float s = scale[bc];
    float4 va = ((const float4*)att0)[i], vo = ((const float4*)outb)[i], v1 = ((const float4*)a1)[i];
    float4 r;
    r.x = va.x * s * vo.x * v1.x; r.y = va.y * s * vo.y * v1.y;
    r.z = va.z * s * vo.z * v1.z; r.w = va.w * s * vo.w * v1.w;
    ((float4*)o)[i] = r;
}

extern "C" void kernel_launch(void* const* d_in, const int* in_sizes, int n_in,
                              void* d_out, int out_size, void* d_ws, size_t ws_size,
                              hipStream_t stream) {
    const float* x1      = (const float*)d_in[0];
    const float* kk      = (const float*)d_in[1];
    const float* conv1_w = (const float*)d_in[2];
    const float* conv1_g = (const float*)d_in[3];
    const float* conv1_b = (const float*)d_in[4];
    const float* conv2_w = (const float*)d_in[5];
    const float* conv2_g = (const float*)d_in[6];
    const float* conv2_b = (const float*)d_in[7];
    const float* conv_w  = (const float*)d_in[8];
    const float* conv_bias = (const float*)d_in[9];
    const float* c0_w  = (const float*)d_in[10];
    const float* c0_g  = (const float*)d_in[11];
    const float* c0_b  = (const float*)d_in[12];
    const float* attc_w = (const float*)d_in[13];
    const float* attc_g = (const float*)d_in[14];
    const float* attc_b = (const float*)d_in[15];
    const float* c05_w = (const float*)d_in[16];
    const float* c05_g = (const float*)d_in[17];
    const float* c05_b = (const float*)d_in[18];
    const float* conv0a_w = (const float*)d_in[19];
    const float* conv0a_g = (const float*)d_in[20];
    const float* conv0a_b = (const float*)d_in[21];
    const float* conv0b_w = (const float*)d_in[22];
    const float* conv0b_g = (const float*)d_in[23];
    const float* conv0b_b = (const float*)d_in[24];
    const float* se_w1 = (const float*)d_in[25];
    const float* se_w2 = (const float*)d_in[26];

    const size_t S = (size_t)8 * 64 * HW;   // 8,388,608 elems per tensor
    float* W  = (float*)d_ws;
    float* s0 = W;            // A1
    float* s1 = W + S;        // att0
    float* s2 = W + 2 * S;    // f1 -> A2 -> finout2 -> out2fin
    float* s3 = W + 3 * S;    // f2 -> outa
    float* s4 = W + 4 * S;    // fuseadd -> out1
    float* s5 = W + 5 * S;    // eadd -> out2conv -> outb
    float* va   = W + 6 * S;        // 8*128
    float* cva  = va + 1024;        // 8*64
    float* sey  = cva + 512;        // 8*64
    float* sesc = sey + 512;        // 8*64
    float* out = (float*)d_out;

    mean_hw_kernel<<<1024, 256, 0, stream>>>(x1, va);                       // va
    convva_kernel<<<1, 512, 0, stream>>>(va, conv_w, cva);                  // conv(va)
    fused_1x1_kernel<<<2048, 256, 0, stream>>>(x1, kk, conv_w, conv1_w, conv2_w,
        cva, conv_bias, conv1_g, conv1_b, conv2_g, conv2_b, s4, s1, s2, s3);
    mean_hw_kernel<<<512, 256, 0, stream>>>(s1, sey);                       // SE pool on att0
    se_mlp_kernel<<<1, 512, 0, stream>>>(sey, se_w1, se_w2, sesc);          // SE scale
    conv3x3_kernel<<<512, 256, 0, stream>>>(s4, c0_w, c0_g, c0_b, nullptr, s5, 0);    // eadd
    conv3x3_kernel<<<512, 256, 0, stream>>>(s5, attc_w, attc_g, attc_b, nullptr, s0, 1); // A1
    conv3x3_kernel<<<512, 256, 0, stream>>>(s2, c0_w, c0_g, c0_b, kk, s4, 2);         // out1 (scaled)
    conv3x3_kernel<<<512, 256, 0, stream>>>(s4, attc_w, attc_g, attc_b, nullptr, s2, 1); // A2
    dyndil_kernel<<<4096, 256, 0, stream>>>(s3, kk, out);                   // out2 -> d_out
    conv5x5_kernel<<<512, 256, 0, stream>>>(out, c05_w, c05_g, c05_b, s5);  // out2conv
    mul3_kernel<<<8192, 256, 0, stream>>>(s0, s2, s5, out);                 // fuseout2 -> d_out
    conv5x5_kernel<<<512, 256, 0, stream>>>(out, c05_w, c05_g, c05_b, s2);  // finout2
    add3_kernel<<<8192, 256, 0, stream>>>(s2, s5, s3, out);                 // eout2 -> d_out
    conv5x5_kernel<<<512, 256, 0, stream>>>(out, c05_w, c05_g, c05_b, s2);  // out2 final
    conv0a_kernel<<<2048, 256, 0, stream>>>(s4, s2, conv0a_w, conv0a_g, conv0a_b, s3); // outa
    conv3x3_kernel<<<512, 256, 0, stream>>>(s3, conv0b_w, conv0b_g, conv0b_b, nullptr, s5, 0); // outb
    final_kernel<<<8192, 256, 0, stream>>>(s1, sesc, s5, s0, out);          // att*out*A1
}

// Round 2
// 2317.482 us; speedup vs baseline: 1.1952x; 1.1952x over previous
//
#include <hip/hip_runtime.h>
#include <math.h>

#define HW 16384
#define EPSC 1.00001f   // 1 + 1e-5

// ---------------- mean over H*W (per (b,c) plane) ----------------
__global__ void mean_hw_kernel(const float* __restrict__ x, float* __restrict__ out) {
    int blk = blockIdx.x;
    const float4* p4 = (const float4*)(x + (size_t)blk * HW);
    float s = 0.f;
    for (int i = threadIdx.x; i < HW / 4; i += 256) {
        float4 v = p4[i];
        s += v.x + v.y + v.z + v.w;
    }
    for (int off = 32; off > 0; off >>= 1) s += __shfl_down(s, off, 64);
    __shared__ float red[4];
    int lane = threadIdx.x & 63, wid = threadIdx.x >> 6;
    if (lane == 0) red[wid] = s;
    __syncthreads();
    if (threadIdx.x == 0)
        out[blk] = (red[0] + red[1] + red[2] + red[3]) * (1.0f / (float)HW);
}

// ---------------- convva[b,co] = sum_ci conv_w[co,ci]*va[b,ci] ----------------
__global__ void convva_kernel(const float* __restrict__ va, const float* __restrict__ cw,
                              float* __restrict__ out) {
    int t = threadIdx.x;           // 512 = 8*64
    int b = t >> 6, co = t & 63;
    float s = 0.f;
    for (int ci = 0; ci < 128; ci++) s = fmaf(cw[co * 128 + ci], va[b * 128 + ci], s);
    out[t] = s;
}

// ---------------- SE MLP: scale[b,c] = sigmoid(leaky(y@w1^T)@w2^T) ----------------
__global__ void se_mlp_kernel(const float* __restrict__ y, const float* __restrict__ w1,
                              const float* __restrict__ w2, float* __restrict__ scale) {
    __shared__ float t[8][4];
    int tid = threadIdx.x;         // 512
    if (tid < 32) {
        int b = tid >> 2, h = tid & 3;
        float s = 0.f;
        for (int ci = 0; ci < 64; ci++) s = fmaf(y[b * 64 + ci], w1[h * 64 + ci], s);
        t[b][h] = s >= 0.f ? s : 0.01f * s;
    }
    __syncthreads();
    int b = tid >> 6, c = tid & 63;
    float s = 0.f;
    for (int h = 0; h < 4; h++) s = fmaf(t[b][h], w2[c * 4 + h], s);
    scale[b * 64 + c] = 1.0f / (1.0f + __expf(-s));
}

// kse bilinear (align-corners) helper: k table is 25 floats for (b,c)
__device__ __forceinline__ float kse_val(const float* kt, int y, int x) {
    float ys = y * (4.0f / 127.0f);
    int y0 = (int)ys; if (y0 > 4) y0 = 4;
    int y1 = min(y0 + 1, 4);
    float wy = ys - (float)y0;
    float xs = x * (4.0f / 127.0f);
    int x0 = (int)xs; if (x0 > 4) x0 = 4;
    int x1 = min(x0 + 1, 4);
    float wx = xs - (float)x0;
    float r0 = kt[y0 * 5 + x0] * (1.f - wx) + kt[y0 * 5 + x1] * wx;
    float r1 = kt[y1 * 5 + x0] * (1.f - wx) + kt[y1 * 5 + x1] * wx;
    return r0 * (1.f - wy) + r1 * wy;
}

// ---------------- fused triple 1x1 conv over x1 ----------------
__global__ __launch_bounds__(256, 2) void fused_1x1_kernel(
    const float* __restrict__ x1, const float* __restrict__ kk,
    const float* __restrict__ cw, const float* __restrict__ c1w, const float* __restrict__ c2w,
    const float* __restrict__ cva, const float* __restrict__ cbias,
    const float* __restrict__ g1, const float* __restrict__ b1,
    const float* __restrict__ g2, const float* __restrict__ b2,
    float* __restrict__ fuseadd, float* __restrict__ att0,
    float* __restrict__ f1, float* __restrict__ f2) {
    __shared__ float xt[128][64];
    __shared__ float wl[3][64][33];
    int b = blockIdx.x >> 8, tile = blockIdx.x & 255;
    int p0 = tile * 64;
    int h = p0 >> 7, w0 = p0 & 127;
    const float* xb = x1 + (size_t)b * 128 * HW + p0;
    for (int e = threadIdx.x; e < 8192; e += 256) {
        int ci = e >> 6, px = e & 63;
        xt[ci][px] = xb[(size_t)ci * HW + px];
    }
    int co = threadIdx.x >> 2, q = threadIdx.x & 3;
    float aw[16], a1[16], a2[16];
#pragma unroll
    for (int j = 0; j < 16; j++) { aw[j] = 0.f; a1[j] = 0.f; a2[j] = 0.f; }
    for (int cc = 0; cc < 128; cc += 32) {
        __syncthreads();
        for (int e = threadIdx.x; e < 2048; e += 256) {
            int c_ = e >> 5, ci = e & 31;
            wl[0][c_][ci] = cw[c_ * 128 + cc + ci];
            wl[1][c_][ci] = c1w[c_ * 128 + cc + ci];
            wl[2][c_][ci] = c2w[c_ * 128 + cc + ci];
        }
        __syncthreads();
        for (int ci = 0; ci < 32; ci++) {
            float w0v = wl[0][co][ci], w1v = wl[1][co][ci], w2v = wl[2][co][ci];
            const float* xr = &xt[cc + ci][q * 16];
#pragma unroll
            for (int j = 0; j < 16; j++) {
                float xv = xr[j];
                aw[j] = fmaf(w0v, xv, aw[j]);
                a1[j] = fmaf(w1v, xv, a1[j]);
                a2[j] = fmaf(w2v, xv, a2[j]);
            }
        }
    }
    float s1v = g1[co] * rsqrtf(EPSC), bb1 = b1[co];
    float s2v = g2[co] * rsqrtf(EPSC), bb2 = b2[co];
    float base = cva[b * 64 + co] + 2.0f * cbias[co];
    const float* kt = kk + (size_t)(b * 64 + co) * 25;
    size_t ob = (size_t)(b * 64 + co) * HW + p0 + q * 16;
#pragma unroll
    for (int j = 0; j < 16; j++) {
        int x = w0 + q * 16 + j;
        float kv = kse_val(kt, h, x);
        float fa = (aw[j] + base) * (1.0f + kv);
        fuseadd[ob + j] = fa;
        att0[ob + j] = 1.0f / (1.0f + __expf(-fa));
        float v1 = fmaf(a1[j], s1v, bb1); f1[ob + j] = v1 >= 0.f ? v1 : 0.01f * v1;
        float v2 = fmaf(a2[j], s2v, bb2); f2[ob + j] = v2 >= 0.f ? v2 : 0.01f * v2;
    }
}

// ---------------- 3x3 conv, 64->64, pad 1. mode: 0=bnlrelu, 1=sigmoid(bnlrelu), 2=bnlrelu*(1+kse)
__global__ __launch_bounds__(256, 2) void conv3x3_kernel(
    const float* __restrict__ x, const float* __restrict__ wgt,
    const float* __restrict__ g, const float* __restrict__ bb,
    const float* __restrict__ kk, float* __restrict__ out, int mode) {
    __shared__ float xl[8][18][20];
    __shared__ float wl[64][73];
    int b = blockIdx.x >> 6, t = blockIdx.x & 63;
    int ty = (t >> 3) * 16, tx = (t & 7) * 16;
    int co = threadIdx.x >> 2, q = threadIdx.x & 3;
    int qy = (q >> 1) * 8, qx = (q & 1) * 8;
    float acc[64];
#pragma unroll
    for (int i = 0; i < 64; i++) acc[i] = 0.f;
    const float* xb = x + (size_t)b * 64 * HW;
    for (int cc = 0; cc < 64; cc += 8) {
        __syncthreads();
        for (int e = threadIdx.x; e < 8 * 18 * 18; e += 256) {
            int ci = e / 324, rem = e % 324, r = rem / 18, c = rem % 18;
            int yy = ty + r - 1, xx = tx + c - 1;
            float v = 0.f;
            if (yy >= 0 && yy < 128 && xx >= 0 && xx < 128)
                v = xb[(size_t)(cc + ci) * HW + yy * 128 + xx];
            xl[ci][r][c] = v;
        }
        for (int e = threadIdx.x; e < 64 * 72; e += 256) {
            int c_ = e / 72, rem = e % 72;
            wl[c_][rem] = wgt[c_ * 576 + cc * 9 + rem];
        }
        __syncthreads();
        for (int ci = 0; ci < 8; ci++) {
            float w[9];
#pragma unroll
            for (int i = 0; i < 9; i++) w[i] = wl[co][ci * 9 + i];
#pragma unroll
            for (int yi = 0; yi < 10; yi++) {
                float r[10];
#pragma unroll
                for (int c = 0; c < 10; c++) r[c] = xl[ci][qy + yi][qx + c];
#pragma unroll
                for (int ky = 0; ky < 3; ky++) {
                    int yo = yi - ky;
                    if (yo >= 0 && yo < 8) {
#pragma unroll
                        for (int xo = 0; xo < 8; xo++) {
                            float s = acc[yo * 8 + xo];
                            s = fmaf(w[ky * 3 + 0], r[xo + 0], s);
                            s = fmaf(w[ky * 3 + 1], r[xo + 1], s);
                            s = fmaf(w[ky * 3 + 2], r[xo + 2], s);
                            acc[yo * 8 + xo] = s;
                        }
                    }
                }
            }
        }
    }
    float sg = g[co] * rsqrtf(EPSC), sb = bb[co];
    size_t ob = (size_t)(b * 64 + co) * HW;
    const float* kt = kk + (size_t)(b * 64 + co) * 25;
#pragma unroll
    for (int yo = 0; yo < 8; yo++) {
        int y = ty + qy + yo;
#pragma unroll
        for (int xo = 0; xo < 8; xo++) {
            int x = tx + qx + xo;
            float v = fmaf(acc[yo * 8 + xo], sg, sb);
            v = v >= 0.f ? v : 0.01f * v;
            if (mode == 1) v = 1.0f / (1.0f + __expf(-v));
            else if (mode == 2) v *= (1.0f + kse_val(kt, y, x));
            out[ob + y * 128 + x] = v;
        }
    }
}

// ---------------- 5x5 conv, 64->64, pad 2, bnlrelu epilogue ----------------
__global__ __launch_bounds__(256, 2) void conv5x5_kernel(
    const float* __restrict__ x, const float* __restrict__ wgt,
    const float* __restrict__ g, const float* __restrict__ bb,
    float* __restrict__ out) {
    __shared__ float xl[4][20][22];
    __shared__ float wl[64][101];
    int b = blockIdx.x >> 6, t = blockIdx.x & 63;
    int ty = (t >> 3) * 16, tx = (t & 7) * 16;
    int co = threadIdx.x >> 2, q = threadIdx.x & 3;
    int qy = (q >> 1) * 8, qx = (q & 1) * 8;
    float acc[64];
#pragma unroll
    for (int i = 0; i < 64; i++) acc[i] = 0.f;
    const float* xb = x + (size_t)b * 64 * HW;
    for (int cc = 0; cc < 64; cc += 4) {
        __syncthreads();
        for (int e = threadIdx.x; e < 4 * 20 * 20; e += 256) {
            int ci = e / 400, rem = e % 400, r = rem / 20, c = rem % 20;
            int yy = ty + r - 2, xx = tx + c - 2;
            float v = 0.f;
            if (yy >= 0 && yy < 128 && xx >= 0 && xx < 128)
                v = xb[(size_t)(cc + ci) * HW + yy * 128 + xx];
            xl[ci][r][c] = v;
        }
        for (int e = threadIdx.x; e < 64 * 100; e += 256) {
            int c_ = e / 100, rem = e % 100;
            wl[c_][rem] = wgt[c_ * 1600 + cc * 25 + rem];
        }
        __syncthreads();
        for (int ci = 0; ci < 4; ci++) {
            float w[25];
#pragma unroll
            for (int i = 0; i < 25; i++) w[i] = wl[co][ci * 25 + i];
#pragma unroll
            for (int yi = 0; yi < 12; yi++) {
                float r[12];
#pragma unroll
                for (int c = 0; c < 12; c++) r[c] = xl[ci][qy + yi][qx + c];
#pragma unroll
                for (int ky = 0; ky < 5; ky++) {
                    int yo = yi - ky;
                    if (yo >= 0 && yo < 8) {
#pragma unroll
                        for (int xo = 0; xo < 8; xo++) {
                            float s = acc[yo * 8 + xo];
                            s = fmaf(w[ky * 5 + 0], r[xo + 0], s);
                            s = fmaf(w[ky * 5 + 1], r[xo + 1], s);
                            s = fmaf(w[ky * 5 + 2], r[xo + 2], s);
                            s = fmaf(w[ky * 5 + 3], r[xo + 3], s);
                            s = fmaf(w[ky * 5 + 4], r[xo + 4], s);
                            acc[yo * 8 + xo] = s;
                        }
                    }
                }
            }
        }
    }
    float sg = g[co] * rsqrtf(EPSC), sb = bb[co];
    size_t ob = (size_t)(b * 64 + co) * HW;
#pragma unroll
    for (int yo = 0; yo < 8; yo++) {
        int y = ty + qy + yo;
#pragma unroll
        for (int xo = 0; xo < 8; xo++) {
            float v = fmaf(acc[yo * 8 + xo], sg, sb);
            v = v >= 0.f ? v : 0.01f * v;
            out[ob + y * 128 + (tx + qx + xo)] = v;
        }
    }
}

// ---------------- dyn multi-dilation depthwise 5x5 (d=1,2,3) + (1+kse), b0 override ----------------
// LDS-staged: block = one (b,c) x 32-row band; halo rows -6..+6 staged once;
// each thread: 16 outputs, 11 register row-windows (8x ds_read_b128 each), 1200 fma.
__global__ __launch_bounds__(256) void dyndil_kernel(const float* __restrict__ f2,
                                                     const float* __restrict__ kk,
                                                     float* __restrict__ out) {
    __shared__ float xl[44][148];   // rows y0-6..y0+37, plane col x stored at col x+8
    int b = blockIdx.x >> 8, c = (blockIdx.x >> 2) & 63, band = blockIdx.x & 3;
    int y0 = band * 32;
    int tid = threadIdx.x;
    int r = tid >> 3, s = tid & 7;
    int x0 = s * 16;
    int y = y0 + r;
    const float* xp = f2 + (size_t)(b * 64 + c) * HW;
    const float* kt = kk + (size_t)(b * 64 + c) * 25;
    float acc[16];

    if (b != 0) {
        for (int e = tid; e < 44 * 148; e += 256) {
            int rr = e / 148, cc = e - rr * 148;
            int yy = y0 + rr - 6, xx = cc - 8;
            float v = 0.f;
            if (yy >= 0 && yy < 128 && xx >= 0 && xx < 128)
                v = xp[yy * 128 + xx];
            xl[rr][cc] = v;
        }
        float kw[25];
#pragma unroll
        for (int i = 0; i < 25; i++) kw[i] = kt[i];
        __syncthreads();
#pragma unroll
        for (int e = 0; e < 16; e++) acc[e] = 0.f;
        int rr = r + 6;
        float win[32];
#define LOADROW(OFF) { const float4* p4 = (const float4*)&xl[rr + (OFF)][x0]; \
        float4 t0=p4[0],t1=p4[1],t2=p4[2],t3=p4[3],t4=p4[4],t5=p4[5],t6=p4[6],t7=p4[7]; \
        win[0]=t0.x;win[1]=t0.y;win[2]=t0.z;win[3]=t0.w; win[4]=t1.x;win[5]=t1.y;win[6]=t1.z;win[7]=t1.w; \
        win[8]=t2.x;win[9]=t2.y;win[10]=t2.z;win[11]=t2.w; win[12]=t3.x;win[13]=t3.y;win[14]=t3.z;win[15]=t3.w; \
        win[16]=t4.x;win[17]=t4.y;win[18]=t4.z;win[19]=t4.w; win[20]=t5.x;win[21]=t5.y;win[22]=t5.z;win[23]=t5.w; \
        win[24]=t6.x;win[25]=t6.y;win[26]=t6.z;win[27]=t6.w; win[28]=t7.x;win[29]=t7.y;win[30]=t7.z;win[31]=t7.w; }
        // win[k] holds plane x = x0 - 8 + k; tap x = x0+e+(j-2)*d -> win[e + 8 + (j-2)*d]
#define APPLY(DIL, I) { \
        _Pragma("unroll") for (int j = 0; j < 5; j++) { \
            float wv = kw[(I)*5 + j]; int o = 8 + (j - 2) * (DIL); \
            _Pragma("unroll") for (int e2 = 0; e2 < 16; e2++) \
                acc[e2] = fmaf(wv, win[e2 + o], acc[e2]); } }
        LOADROW(-6) APPLY(3,0)
        LOADROW(-4) APPLY(2,0)
        LOADROW(-3) APPLY(3,1)
        LOADROW(-2) APPLY(1,0) APPLY(2,1)
        LOADROW(-1) APPLY(1,1)
        LOADROW(0)  APPLY(1,2) APPLY(2,2) APPLY(3,2)
        LOADROW(1)  APPLY(1,3)
        LOADROW(2)  APPLY(1,4) APPLY(2,3)
        LOADROW(3)  APPLY(3,3)
        LOADROW(4)  APPLY(2,4)
        LOADROW(6)  APPLY(3,4)
#undef LOADROW
#undef APPLY
    } else {
        const float4* p4 = (const float4*)(xp + y * 128 + x0);
#pragma unroll
        for (int i = 0; i < 4; i++) {
            float4 v = p4[i];
            acc[i*4] = v.x; acc[i*4+1] = v.y; acc[i*4+2] = v.z; acc[i*4+3] = v.w;
        }
    }
    // epilogue: *(1+kse), y-part hoisted, x-part via register selects
    float ys = y * (4.0f / 127.0f);
    int yi0 = (int)ys; if (yi0 > 4) yi0 = 4;
    int yi1 = yi0 + 1; if (yi1 > 4) yi1 = 4;
    float wy = ys - (float)yi0;
    float ry0 = kt[yi0*5+0] * (1.f-wy) + kt[yi1*5+0] * wy;
    float ry1 = kt[yi0*5+1] * (1.f-wy) + kt[yi1*5+1] * wy;
    float ry2 = kt[yi0*5+2] * (1.f-wy) + kt[yi1*5+2] * wy;
    float ry3 = kt[yi0*5+3] * (1.f-wy) + kt[yi1*5+3] * wy;
    float ry4 = kt[yi0*5+4] * (1.f-wy) + kt[yi1*5+4] * wy;
    float res[16];
#pragma unroll
    for (int e = 0; e < 16; e++) {
        int x = x0 + e;
        float xs = x * (4.0f / 127.0f);
        int xi0 = (int)xs; if (xi0 > 4) xi0 = 4;
        float wx = xs - (float)xi0;
        float a = xi0==0 ? ry0 : xi0==1 ? ry1 : xi0==2 ? ry2 : xi0==3 ? ry3 : ry4;
        float bs = xi0>=3 ? ry4 : (xi0==2 ? ry3 : (xi0==1 ? ry2 : ry1));
        float kv = a + (bs - a) * wx;
        res[e] = acc[e] * (1.0f + kv);
    }
    float* op = out + (size_t)(b * 64 + c) * HW + (size_t)y * 128 + x0;
#pragma unroll
    for (int i = 0; i < 4; i++) {
        float4 v = { res[i*4], res[i*4+1], res[i*4+2], res[i*4+3] };
        ((float4*)op)[i] = v;
    }
}

// ---------------- 1x1 conv over concat([xa,xb]) (128 -> 64) + bnlrelu ----------------
__global__ __launch_bounds__(256, 2) void conv0a_kernel(
    const float* __restrict__ xa, const float* __restrict__ xb2,
    const float* __restrict__ wgt, const float* __restrict__ g, const float* __restrict__ bb,
    float* __restrict__ out) {
    __shared__ float xt[128][64];
    __shared__ float wl[64][33];
    int b = blockIdx.x >> 8, tile = blockIdx.x & 255;
    int p0 = tile * 64;
    const float* pa = xa + (size_t)b * 64 * HW + p0;
    const float* pb = xb2 + (size_t)b * 64 * HW + p0;
    for (int e = threadIdx.x; e < 4096; e += 256) {
        int ci = e >> 6, px = e & 63;
        xt[ci][px] = pa[(size_t)ci * HW + px];
        xt[64 + ci][px] = pb[(size_t)ci * HW + px];
    }
    int co = threadIdx.x >> 2, q = threadIdx.x & 3;
    float acc[16];
#pragma unroll
    for (int j = 0; j < 16; j++) acc[j] = 0.f;
    for (int cc = 0; cc < 128; cc += 32) {
        __syncthreads();
        for (int e = threadIdx.x; e < 2048; e += 256) {
            int c_ = e >> 5, ci = e & 31;
            wl[c_][ci] = wgt[c_ * 128 + cc + ci];
        }
        __syncthreads();
        for (int ci = 0; ci < 32; ci++) {
            float w = wl[co][ci];
            const float* xr = &xt[cc + ci][q * 16];
#pragma unroll
            for (int j = 0; j < 16; j++) acc[j] = fmaf(w, xr[j], acc[j]);
        }
    }
    float sg = g[co] * rsqrtf(EPSC), sb = bb[co];
    size_t ob = (size_t)(b * 64 + co) * HW + p0 + q * 16;
#pragma unroll
    for (int j = 0; j < 16; j++) {
        float v = fmaf(acc[j], sg, sb);
        out[ob + j] = v >= 0.f ? v : 0.01f * v;
    }
}

// ---------------- elementwise ----------------
__global__ void mul3_kernel(const float* __restrict__ a, const float* __restrict__ b,
                            const float* __restrict__ c, float* __restrict__ o) {
    size_t i = ((size_t)blockIdx.x * 256 + threadIdx.x);
    float4 va = ((const float4*)a)[i], vb = ((const float4*)b)[i], vc = ((const float4*)c)[i];
    float4 r;
    r.x = va.x * vb.x * vc.x; r.y = va.y * vb.y * vc.y;
    r.z = va.z * vb.z * vc.z; r.w = va.w * vb.w * vc.w;
    ((float4*)o)[i] = r;
}

__global__ void add3_kernel(const float* __restrict__ a, const float* __restrict__ b,
                            const float* __restrict__ c, float* __restrict__ o) {
    size_t i = ((size_t)blockIdx.x * 256 + threadIdx.x);
    float4 va = ((const float4*)a)[i], vb = ((const float4*)b)[i], vc = ((const float4*)c)[i];
    float4 r;
    r.x = va.x + vb.x + vc.x; r.y = va.y + vb.y + vc.y;
    r.z = va.z + vb.z + vc.z; r.w = va.w + vb.w + vc.w;
    ((float4*)o)[i] = r;
}

__global__ void final_kernel(const float* __restrict__ att0, const float* __restrict__ scale,
                             const float* __restrict__ outb, const float* __restrict__ a1,
                             float* __restrict__ o) {
    size_t i = ((size_t)blockIdx.x * 256 + threadIdx.x);
    int bc = (int)((i * 4) >> 14);
    float s = scale[bc];
    float4 va = ((const float4*)att0)[i], vo = ((const float4*)outb)[i], v1 = ((const float4*)a1)[i];
    float4 r;
    r.x = va.x * s * vo.x * v1.x; r.y = va.y * s * vo.y * v1.y;
    r.z = va.z * s * vo.z * v1.z; r.w = va.w * s * vo.w * v1.w;
    ((float4*)o)[i] = r;
}

extern "C" void kernel_launch(void* const* d_in, const int* in_sizes, int n_in,
                              void* d_out, int out_size, void* d_ws, size_t ws_size,
                              hipStream_t stream) {
    const float* x1      = (const float*)d_in[0];
    const float* kk      = (const float*)d_in[1];
    const float* conv1_w = (const float*)d_in[2];
    const float* conv1_g = (const float*)d_in[3];
    const float* conv1_b = (const float*)d_in[4];
    const float* conv2_w = (const float*)d_in[5];
    const float* conv2_g = (const float*)d_in[6];
    const float* conv2_b = (const float*)d_in[7];
    const float* conv_w  = (const float*)d_in[8];
    const float* conv_bias = (const float*)d_in[9];
    const float* c0_w  = (const float*)d_in[10];
    const float* c0_g  = (const float*)d_in[11];
    const float* c0_b  = (const float*)d_in[12];
    const float* attc_w = (const float*)d_in[13];
    const float* attc_g = (const float*)d_in[14];
    const float* attc_b = (const float*)d_in[15];
    const float* c05_w = (const float*)d_in[16];
    const float* c05_g = (const float*)d_in[17];
    const float* c05_b = (const float*)d_in[18];
    const float* conv0a_w = (const float*)d_in[19];
    const float* conv0a_g = (const float*)d_in[20];
    const float* conv0a_b = (const float*)d_in[21];
    const float* conv0b_w = (const float*)d_in[22];
    const float* conv0b_g = (const float*)d_in[23];
    const float* conv0b_b = (const float*)d_in[24];
    const float* se_w1 = (const float*)d_in[25];
    const float* se_w2 = (const float*)d_in[26];

    const size_t S = (size_t)8 * 64 * HW;   // 8,388,608 elems per tensor
    float* W  = (float*)d_ws;
    float* s0 = W;            // A1
    float* s1 = W + S;        // att0
    float* s2 = W + 2 * S;    // f1 -> A2 -> finout2 -> out2fin
    float* s3 = W + 3 * S;    // f2 -> outa
    float* s4 = W + 4 * S;    // fuseadd -> out1
    float* s5 = W + 5 * S;    // eadd -> out2conv -> outb
    float* va   = W + 6 * S;        // 8*128
    float* cva  = va + 1024;        // 8*64
    float* sey  = cva + 512;        // 8*64
    float* sesc = sey + 512;        // 8*64
    float* out = (float*)d_out;

    mean_hw_kernel<<<1024, 256, 0, stream>>>(x1, va);                       // va
    convva_kernel<<<1, 512, 0, stream>>>(va, conv_w, cva);                  // conv(va)
    fused_1x1_kernel<<<2048, 256, 0, stream>>>(x1, kk, conv_w, conv1_w, conv2_w,
        cva, conv_bias, conv1_g, conv1_b, conv2_g, conv2_b, s4, s1, s2, s3);
    mean_hw_kernel<<<512, 256, 0, stream>>>(s1, sey);                       // SE pool on att0
    se_mlp_kernel<<<1, 512, 0, stream>>>(sey, se_w1, se_w2, sesc);          // SE scale
    conv3x3_kernel<<<512, 256, 0, stream>>>(s4, c0_w, c0_g, c0_b, nullptr, s5, 0);    // eadd
    conv3x3_kernel<<<512, 256, 0, stream>>>(s5, attc_w, attc_g, attc_b, nullptr, s0, 1); // A1
    conv3x3_kernel<<<512, 256, 0, stream>>>(s2, c0_w, c0_g, c0_b, kk, s4, 2);         // out1 (scaled)
    conv3x3_kernel<<<512, 256, 0, stream>>>(s4, attc_w, attc_g, attc_b, nullptr, s2, 1); // A2
    dyndil_kernel<<<2048, 256, 0, stream>>>(s3, kk, out);                   // out2 -> d_out
    conv5x5_kernel<<<512, 256, 0, stream>>>(out, c05_w, c05_g, c05_b, s5);  // out2conv
    mul3_kernel<<<8192, 256, 0, stream>>>(s0, s2, s5, out);                 // fuseout2 -> d_out
    conv5x5_kernel<<<512, 256, 0, stream>>>(out, c05_w, c05_g, c05_b, s2);  // finout2
    add3_kernel<<<8192, 256, 0, stream>>>(s2, s5, s3, out);                 // eout2 -> d_out
    conv5x5_kernel<<<512, 256, 0, stream>>>(out, c05_w, c05_g, c05_b, s2);  // out2 final
    conv0a_kernel<<<2048, 256, 0, stream>>>(s4, s2, conv0a_w, conv0a_g, conv0a_b, s3); // outa
    conv3x3_kernel<<<512, 256, 0, stream>>>(s3, conv0b_w, conv0b_g, conv0b_b, nullptr, s5, 0); // outb
    final_kernel<<<8192, 256, 0, stream>>>(s1, sesc, s5, s0, out);          // att*out*A1
}

// Round 3
// 796.548 us; speedup vs baseline: 3.4773x; 2.9094x over previous
//
#include <hip/hip_runtime.h>
#include <math.h>

#define HW 16384
#define EPSC 1.00001f   // 1 + 1e-5

typedef short bf16x8 __attribute__((ext_vector_type(8)));
typedef float f32x4 __attribute__((ext_vector_type(4)));

static __device__ __forceinline__ unsigned short f2bf(float f) {
    unsigned int u = __float_as_uint(f);
    unsigned int r = (u + 0x7fffu + ((u >> 16) & 1u)) >> 16;
    return (unsigned short)r;
}
static __device__ __forceinline__ float bf2f(unsigned short u) {
    return __uint_as_float(((unsigned int)u) << 16);
}

// ---------------- mean over H*W (per (b,c) plane) ----------------
__global__ void mean_hw_kernel(const float* __restrict__ x, float* __restrict__ out) {
    int blk = blockIdx.x;
    const float4* p4 = (const float4*)(x + (size_t)blk * HW);
    float s = 0.f;
    for (int i = threadIdx.x; i < HW / 4; i += 256) {
        float4 v = p4[i];
        s += v.x + v.y + v.z + v.w;
    }
    for (int off = 32; off > 0; off >>= 1) s += __shfl_down(s, off, 64);
    __shared__ float red[4];
    int lane = threadIdx.x & 63, wid = threadIdx.x >> 6;
    if (lane == 0) red[wid] = s;
    __syncthreads();
    if (threadIdx.x == 0)
        out[blk] = (red[0] + red[1] + red[2] + red[3]) * (1.0f / (float)HW);
}

// ---------------- convva[b,co] = sum_ci conv_w[co,ci]*va[b,ci] ----------------
__global__ void convva_kernel(const float* __restrict__ va, const float* __restrict__ cw,
                              float* __restrict__ out) {
    int t = threadIdx.x;           // 512 = 8*64
    int b = t >> 6, co = t & 63;
    float s = 0.f;
    for (int ci = 0; ci < 128; ci++) s = fmaf(cw[co * 128 + ci], va[b * 128 + ci], s);
    out[t] = s;
}

// ---------------- SE MLP ----------------
__global__ void se_mlp_kernel(const float* __restrict__ y, const float* __restrict__ w1,
                              const float* __restrict__ w2, float* __restrict__ scale) {
    __shared__ float t[8][4];
    int tid = threadIdx.x;         // 512
    if (tid < 32) {
        int b = tid >> 2, h = tid & 3;
        float s = 0.f;
        for (int ci = 0; ci < 64; ci++) s = fmaf(y[b * 64 + ci], w1[h * 64 + ci], s);
        t[b][h] = s >= 0.f ? s : 0.01f * s;
    }
    __syncthreads();
    int b = tid >> 6, c = tid & 63;
    float s = 0.f;
    for (int h = 0; h < 4; h++) s = fmaf(t[b][h], w2[c * 4 + h], s);
    scale[b * 64 + c] = 1.0f / (1.0f + __expf(-s));
}

// kse bilinear (align-corners): k table is 25 floats for (b,c)
__device__ __forceinline__ float kse_val(const float* kt, int y, int x) {
    float ys = y * (4.0f / 127.0f);
    int y0 = (int)ys; if (y0 > 4) y0 = 4;
    int y1 = min(y0 + 1, 4);
    float wy = ys - (float)y0;
    float xs = x * (4.0f / 127.0f);
    int x0 = (int)xs; if (x0 > 4) x0 = 4;
    int x1 = min(x0 + 1, 4);
    float wx = xs - (float)x0;
    float r0 = kt[y0 * 5 + x0] * (1.f - wx) + kt[y0 * 5 + x1] * wx;
    float r1 = kt[y1 * 5 + x0] * (1.f - wx) + kt[y1 * 5 + x1] * wx;
    return r0 * (1.f - wy) + r1 * wy;
}

// ---------------- repack x1 f32 NCHW[128][HW] -> two bf16 NHWC [HW][64] ----------------
__global__ void repack_x1_kernel(const float* __restrict__ x1,
                                 unsigned short* __restrict__ xa,
                                 unsigned short* __restrict__ xb) {
    __shared__ float t[64][65];
    int b = blockIdx.y;
    int p0 = blockIdx.x * 64;
    for (int h = 0; h < 2; ++h) {
        const float* src = x1 + ((size_t)b * 128 + h * 64) * HW + p0;
        __syncthreads();
        for (int e = threadIdx.x; e < 4096; e += 256) {
            int ci = e >> 6, px = e & 63;
            t[ci][px] = src[(size_t)ci * HW + px];
        }
        __syncthreads();
        unsigned short* dst = (h == 0 ? xa : xb) + ((size_t)b * HW + p0) * 64;
        for (int e = threadIdx.x; e < 4096; e += 256) {
            int px = e >> 6, ci = e & 63;
            dst[(size_t)px * 64 + ci] = f2bf(t[ci][px]);
        }
    }
}

// ---------------- weight pack: [co][ci][k][k] f32 -> [kc][co_total][32] bf16 ----------------
__global__ void prep_w_kernel(const float* __restrict__ src, unsigned short* __restrict__ dst,
                              int CO, int CI, int K, int co_total, int co_off) {
    int idx = blockIdx.x * 256 + threadIdx.x;
    int total = CO * CI * K * K;
    if (idx >= total) return;
    int kx = idx % K, t1 = idx / K;
    int ky = t1 % K, t2 = t1 / K;
    int ci = t2 % CI, co = t2 / CI;
    int tap = ky * K + kx, chunk = ci >> 5, k32 = ci & 31;
    int kc = tap * (CI >> 5) + chunk;
    dst[((size_t)kc * co_total + co_off + co) * 32 + k32] = f2bf(src[idx]);
}

// ---------------- MFMA implicit conv ----------------
// Block: 64 co x (TH x 16) px.  X input NHWC bf16 (stride 64 per tensor; CI=128 uses Xa+Xb).
// Weights Wp[kc][wco][32] bf16 (kc = tap*(CI/32)+chunk).
// emode: 0=bnlrelu  1=sigmoid(bnlrelu)  2=bnlrelu*(1+kse)
//        3=fuseadd special (cva/cbias/kse -> out_bf=fuseadd, out_f32=att0=sigmoid)
//        4=bnlrelu -> out_bf; aux_bf = eA(f32 NCHW) * eB(bf16 NHWC) * v
//        5=bnlrelu + eB(bf16 NHWC) + eC(f32 NCHW) -> out_bf
template<int KSZ, int CI, int TH>
__global__ __launch_bounds__(256, 2) void conv_mfma(
    const unsigned short* __restrict__ Xa, const unsigned short* __restrict__ Xb,
    const unsigned short* __restrict__ Wp, int wco, int cob,
    const float* __restrict__ g, const float* __restrict__ bb,
    const float* __restrict__ kk,
    const float* __restrict__ cva, const float* __restrict__ cbias,
    const float* __restrict__ eA, const unsigned short* __restrict__ eB,
    const float* __restrict__ eC,
    float* __restrict__ out_f32, unsigned short* __restrict__ out_bf,
    unsigned short* __restrict__ aux_bf, int emode)
{
    constexpr int PAD = KSZ / 2;
    constexpr int TWX = 16 + 2 * PAD;          // tile width incl halo
    constexpr int TWY = TH + 2 * PAD;          // tile height incl halo
    constexpr int CIP = CI + 8;                // padded px stride (bank-conflict break)
    constexpr int CHUNKS = CI / 32;
    constexpr int NT = TH / 4;                 // N-tiles (rows) per wave
    constexpr int CI8 = CI / 8;
    constexpr int CI8SH = (CI == 64) ? 3 : 4;
    __shared__ unsigned short xs[TWY * TWX * CIP];

    const int b = blockIdx.y;
    const int ty = (blockIdx.x >> 3) * TH, tx = (blockIdx.x & 7) * 16;
    const int tid = threadIdx.x;
    const int lane = tid & 63, wv = tid >> 6;
    const int n = lane & 15, quad = lane >> 4;

    // ---- stage X tile (NHWC: contiguous 16B per 8 ci) ----
    for (int e = tid; e < TWY * TWX * CI8; e += 256) {
        int ci8 = e & (CI8 - 1);
        int pxl = e >> CI8SH;
        int xx = pxl % TWX, yy = pxl / TWX;
        int gy = ty + yy - PAD, gx = tx + xx - PAD;
        uint4 v = {0u, 0u, 0u, 0u};
        if (gy >= 0 && gy < 128 && gx >= 0 && gx < 128) {
            const unsigned short* src = Xa;
            int c8 = ci8;
            if (CI == 128 && ci8 >= 8) { src = Xb; c8 = ci8 - 8; }
            v = *(const uint4*)(src + (((size_t)b * HW + gy * 128 + gx) * 64 + c8 * 8));
        }
        *(uint4*)(&xs[pxl * CIP + ci8 * 8]) = v;
    }
    __syncthreads();

    f32x4 acc[4][NT];
#pragma unroll
    for (int mb = 0; mb < 4; ++mb)
#pragma unroll
        for (int nt = 0; nt < NT; ++nt) acc[mb][nt] = (f32x4){0.f, 0.f, 0.f, 0.f};

    const int r0 = wv * NT;
    for (int ky = 0; ky < KSZ; ++ky) {
        for (int kx = 0; kx < KSZ; ++kx) {
#pragma unroll
            for (int ch = 0; ch < CHUNKS; ++ch) {
                const int kc = (ky * KSZ + kx) * CHUNKS + ch;
                bf16x8 af[4];
#pragma unroll
                for (int mb = 0; mb < 4; ++mb)
                    af[mb] = *(const bf16x8*)(Wp +
                        ((size_t)(kc * wco + cob + mb * 16 + n) * 32 + quad * 8));
                bf16x8 bfr[NT];
#pragma unroll
                for (int nt = 0; nt < NT; ++nt)
                    bfr[nt] = *(const bf16x8*)(&xs[((r0 + nt + ky) * TWX + (n + kx)) * CIP +
                                                   ch * 32 + quad * 8]);
#pragma unroll
                for (int mb = 0; mb < 4; ++mb)
#pragma unroll
                    for (int nt = 0; nt < NT; ++nt)
                        acc[mb][nt] = __builtin_amdgcn_mfma_f32_16x16x32_bf16(
                            af[mb], bfr[nt], acc[mb][nt], 0, 0, 0);
            }
        }
    }

    // ---- epilogue.  D layout: row(co)=quad*4+reg, col(px)=lane&15 ----
    const float rs = rsqrtf(EPSC);
#pragma unroll
    for (int mb = 0; mb < 4; ++mb) {
#pragma unroll
        for (int nt = 0; nt < NT; ++nt) {
            const int py = ty + r0 + nt;
            const int px = tx + n;
            const size_t pix = (size_t)b * HW + py * 128 + px;
            const int co0 = mb * 16 + quad * 4;
            float v4[4];
#pragma unroll
            for (int rg = 0; rg < 4; ++rg) {
                int co = co0 + rg;
                float v = acc[mb][nt][rg];
                if (emode == 3) {
                    float base = cva[b * 64 + co] + 2.0f * cbias[co];
                    v = (v + base) * (1.0f + kse_val(kk + (size_t)(b * 64 + co) * 25, py, px));
                } else {
                    v = fmaf(v, g[co] * rs, bb[co]);
                    v = v >= 0.f ? v : 0.01f * v;
                    if (emode == 1) v = 1.0f / (1.0f + __expf(-v));
                    else if (emode == 2)
                        v *= (1.0f + kse_val(kk + (size_t)(b * 64 + co) * 25, py, px));
                }
                v4[rg] = v;
            }
            if (emode == 3) {
                ushort4 pk = {f2bf(v4[0]), f2bf(v4[1]), f2bf(v4[2]), f2bf(v4[3])};
                *(ushort4*)(out_bf + pix * 64 + co0) = pk;
#pragma unroll
                for (int rg = 0; rg < 4; ++rg)
                    out_f32[(size_t)(b * 64 + co0 + rg) * HW + py * 128 + px] =
                        1.0f / (1.0f + __expf(-v4[rg]));
            } else if (emode == 4) {
                ushort4 pk = {f2bf(v4[0]), f2bf(v4[1]), f2bf(v4[2]), f2bf(v4[3])};
                *(ushort4*)(out_bf + pix * 64 + co0) = pk;
                ushort4 a2 = *(const ushort4*)(eB + pix * 64 + co0);
                float m0 = eA[(size_t)(b * 64 + co0 + 0) * HW + py * 128 + px] * bf2f(a2.x) * v4[0];
                float m1 = eA[(size_t)(b * 64 + co0 + 1) * HW + py * 128 + px] * bf2f(a2.y) * v4[1];
                float m2 = eA[(size_t)(b * 64 + co0 + 2) * HW + py * 128 + px] * bf2f(a2.z) * v4[2];
                float m3 = eA[(size_t)(b * 64 + co0 + 3) * HW + py * 128 + px] * bf2f(a2.w) * v4[3];
                ushort4 pk2 = {f2bf(m0), f2bf(m1), f2bf(m2), f2bf(m3)};
                *(ushort4*)(aux_bf + pix * 64 + co0) = pk2;
            } else if (emode == 5) {
                ushort4 oc = *(const ushort4*)(eB + pix * 64 + co0);
                float r0v = v4[0] + bf2f(oc.x) + eC[(size_t)(b * 64 + co0 + 0) * HW + py * 128 + px];
                float r1v = v4[1] + bf2f(oc.y) + eC[(size_t)(b * 64 + co0 + 1) * HW + py * 128 + px];
                float r2v = v4[2] + bf2f(oc.z) + eC[(size_t)(b * 64 + co0 + 2) * HW + py * 128 + px];
                float r3v = v4[3] + bf2f(oc.w) + eC[(size_t)(b * 64 + co0 + 3) * HW + py * 128 + px];
                ushort4 pk = {f2bf(r0v), f2bf(r1v), f2bf(r2v), f2bf(r3v)};
                *(ushort4*)(out_bf + pix * 64 + co0) = pk;
            } else {
                if (out_bf) {
                    ushort4 pk = {f2bf(v4[0]), f2bf(v4[1]), f2bf(v4[2]), f2bf(v4[3])};
                    *(ushort4*)(out_bf + pix * 64 + co0) = pk;
                }
                if (out_f32) {
#pragma unroll
                    for (int rg = 0; rg < 4; ++rg)
                        out_f32[(size_t)(b * 64 + co0 + rg) * HW + py * 128 + px] = v4[rg];
                }
            }
        }
    }
}

// ---------------- dyn multi-dilation depthwise 5x5 (d=1,2,3) + (1+kse); bf16 NHWC out ----------------
__global__ __launch_bounds__(256) void dyndil_kernel(const float* __restrict__ f2,
                                                     const float* __restrict__ kk,
                                                     unsigned short* __restrict__ out2bf) {
    __shared__ float xl[44][148];
    int b = blockIdx.x >> 8, c = (blockIdx.x >> 2) & 63, band = blockIdx.x & 3;
    int y0 = band * 32;
    int tid = threadIdx.x;
    int r = tid >> 3, s = tid & 7;
    int x0 = s * 16;
    int y = y0 + r;
    const float* xp = f2 + (size_t)(b * 64 + c) * HW;
    const float* kt = kk + (size_t)(b * 64 + c) * 25;
    float acc[16];

    if (b != 0) {
        for (int e = tid; e < 44 * 148; e += 256) {
            int rr = e / 148, cc = e - rr * 148;
            int yy = y0 + rr - 6, xx = cc - 8;
            float v = 0.f;
            if (yy >= 0 && yy < 128 && xx >= 0 && xx < 128)
                v = xp[yy * 128 + xx];
            xl[rr][cc] = v;
        }
        float kw[25];
#pragma unroll
        for (int i = 0; i < 25; i++) kw[i] = kt[i];
        __syncthreads();
#pragma unroll
        for (int e = 0; e < 16; e++) acc[e] = 0.f;
        int rr = r + 6;
        float win[32];
#define LOADROW(OFF) { const float4* p4 = (const float4*)&xl[rr + (OFF)][x0]; \
        float4 t0=p4[0],t1=p4[1],t2=p4[2],t3=p4[3],t4=p4[4],t5=p4[5],t6=p4[6],t7=p4[7]; \
        win[0]=t0.x;win[1]=t0.y;win[2]=t0.z;win[3]=t0.w; win[4]=t1.x;win[5]=t1.y;win[6]=t1.z;win[7]=t1.w; \
        win[8]=t2.x;win[9]=t2.y;win[10]=t2.z;win[11]=t2.w; win[12]=t3.x;win[13]=t3.y;win[14]=t3.z;win[15]=t3.w; \
        win[16]=t4.x;win[17]=t4.y;win[18]=t4.z;win[19]=t4.w; win[20]=t5.x;win[21]=t5.y;win[22]=t5.z;win[23]=t5.w; \
        win[24]=t6.x;win[25]=t6.y;win[26]=t6.z;win[27]=t6.w; win[28]=t7.x;win[29]=t7.y;win[30]=t7.z;win[31]=t7.w; }
#define APPLY(DIL, I) { \
        _Pragma("unroll") for (int j = 0; j < 5; j++) { \
            float wv = kw[(I)*5 + j]; int o = 8 + (j - 2) * (DIL); \
            _Pragma("unroll") for (int e2 = 0; e2 < 16; e2++) \
                acc[e2] = fmaf(wv, win[e2 + o], acc[e2]); } }
        LOADROW(-6) APPLY(3,0)
        LOADROW(-4) APPLY(2,0)
        LOADROW(-3) APPLY(3,1)
        LOADROW(-2) APPLY(1,0) APPLY(2,1)
        LOADROW(-1) APPLY(1,1)
        LOADROW(0)  APPLY(1,2) APPLY(2,2) APPLY(3,2)
        LOADROW(1)  APPLY(1,3)
        LOADROW(2)  APPLY(1,4) APPLY(2,3)
        LOADROW(3)  APPLY(3,3)
        LOADROW(4)  APPLY(2,4)
        LOADROW(6)  APPLY(3,4)
#undef LOADROW
#undef APPLY
    } else {
        const float4* p4 = (const float4*)(xp + y * 128 + x0);
#pragma unroll
        for (int i = 0; i < 4; i++) {
            float4 v = p4[i];
            acc[i*4] = v.x; acc[i*4+1] = v.y; acc[i*4+2] = v.z; acc[i*4+3] = v.w;
        }
    }
    float ys = y * (4.0f / 127.0f);
    int yi0 = (int)ys; if (yi0 > 4) yi0 = 4;
    int yi1 = yi0 + 1; if (yi1 > 4) yi1 = 4;
    float wy = ys - (float)yi0;
    float ry0 = kt[yi0*5+0] * (1.f-wy) + kt[yi1*5+0] * wy;
    float ry1 = kt[yi0*5+1] * (1.f-wy) + kt[yi1*5+1] * wy;
    float ry2 = kt[yi0*5+2] * (1.f-wy) + kt[yi1*5+2] * wy;
    float ry3 = kt[yi0*5+3] * (1.f-wy) + kt[yi1*5+3] * wy;
    float ry4 = kt[yi0*5+4] * (1.f-wy) + kt[yi1*5+4] * wy;
    unsigned short* op = out2bf + ((size_t)b * HW + (size_t)y * 128 + x0) * 64 + c;
#pragma unroll
    for (int e = 0; e < 16; e++) {
        int x = x0 + e;
        float xs2 = x * (4.0f / 127.0f);
        int xi0 = (int)xs2; if (xi0 > 4) xi0 = 4;
        float wx = xs2 - (float)xi0;
        float a = xi0==0 ? ry0 : xi0==1 ? ry1 : xi0==2 ? ry2 : xi0==3 ? ry3 : ry4;
        float bs = xi0>=3 ? ry4 : (xi0==2 ? ry3 : (xi0==1 ? ry2 : ry1));
        float kv = a + (bs - a) * wx;
        op[(size_t)e * 64] = f2bf(acc[e] * (1.0f + kv));
    }
}

// ---------------- final: att0 * sesc * outb * A1 ----------------
__global__ void final_kernel(const float* __restrict__ att0, const float* __restrict__ scale,
                             const float* __restrict__ outb, const float* __restrict__ a1,
                             float* __restrict__ o) {
    size_t i = ((size_t)blockIdx.x * 256 + threadIdx.x);
    int bc = (int)((i * 4) >> 14);
    float s = scale[bc];
    float4 va = ((const float4*)att0)[i], vo = ((const float4*)outb)[i], v1 = ((const float4*)a1)[i];
    float4 r;
    r.x = va.x * s * vo.x * v1.x; r.y = va.y * s * vo.y * v1.y;
    r.z = va.z * s * vo.z * v1.z; r.w = va.w * s * vo.w * v1.w;
    ((float4*)o)[i] = r;
}

extern "C" void kernel_launch(void* const* d_in, const int* in_sizes, int n_in,
                              void* d_out, int out_size, void* d_ws, size_t ws_size,
                              hipStream_t stream) {
    const float* x1      = (const float*)d_in[0];
    const float* kk      = (const float*)d_in[1];
    const float* conv1_w = (const float*)d_in[2];
    const float* conv1_g = (const float*)d_in[3];
    const float* conv1_b = (const float*)d_in[4];
    const float* conv2_w = (const float*)d_in[5];
    const float* conv2_g = (const float*)d_in[6];
    const float* conv2_b = (const float*)d_in[7];
    const float* conv_w  = (const float*)d_in[8];
    const float* conv_bias = (const float*)d_in[9];
    const float* c0_w  = (const float*)d_in[10];
    const float* c0_g  = (const float*)d_in[11];
    const float* c0_b  = (const float*)d_in[12];
    const float* attc_w = (const float*)d_in[13];
    const float* attc_g = (const float*)d_in[14];
    const float* attc_b = (const float*)d_in[15];
    const float* c05_w = (const float*)d_in[16];
    const float* c05_g = (const float*)d_in[17];
    const float* c05_b = (const float*)d_in[18];
    const float* conv0a_w = (const float*)d_in[19];
    const float* conv0a_g = (const float*)d_in[20];
    const float* conv0a_b = (const float*)d_in[21];
    const float* conv0b_w = (const float*)d_in[22];
    const float* conv0b_g = (const float*)d_in[23];
    const float* conv0b_b = (const float*)d_in[24];
    const float* se_w1 = (const float*)d_in[25];
    const float* se_w2 = (const float*)d_in[26];

    // ---- workspace layout: 16 MB bf16-units ----
    const size_t U = (size_t)8 * HW * 64 * 2;           // 16,777,216 B
    unsigned char* P = (unsigned char*)d_ws;
    unsigned short* x1a      = (unsigned short*)(P + 0 * U);   // -> eout2_bf
    unsigned short* x1b      = (unsigned short*)(P + 1 * U);   // -> out2fin_bf
    float*          att0     = (float*)         (P + 2 * U);   // 2 units
    unsigned short* fuse_bf  = (unsigned short*)(P + 4 * U);   // -> out2_bf
    unsigned short* f1_bf    = (unsigned short*)(P + 5 * U);   // -> fuseout2_bf
    float*          f2       = (float*)         (P + 6 * U);   // 2 units -> outb
    float*          A1       = (float*)         (P + 8 * U);   // 2 units
    unsigned short* eadd_bf  = (unsigned short*)(P + 10 * U);  // -> outa_bf
    unsigned short* out1_bf  = (unsigned short*)(P + 11 * U);
    unsigned short* A2_bf    = (unsigned short*)(P + 12 * U);
    unsigned short* oc_bf    = (unsigned short*)(P + 13 * U);  // out2conv bf16
    unsigned short* eout2_bf   = x1a;
    unsigned short* out2fin_bf = x1b;
    unsigned short* out2_bf    = fuse_bf;
    unsigned short* fuseout2_bf = f1_bf;
    float*          outb       = f2;
    unsigned short* outa_bf    = eadd_bf;
    unsigned char* W0 = P + 14 * U;
    unsigned short* Wp1   = (unsigned short*)(W0);             // 192*128*2   = 49152
    unsigned short* Wc0   = (unsigned short*)(W0 + 49152);     // 64*64*9*2   = 73728
    unsigned short* Wattc = (unsigned short*)(W0 + 122880);    // 73728
    unsigned short* Wc05  = (unsigned short*)(W0 + 196608);    // 64*64*25*2  = 204800
    unsigned short* Wc0a  = (unsigned short*)(W0 + 401408);    // 64*128*2    = 16384
    unsigned short* Wc0b  = (unsigned short*)(W0 + 417792);    // 73728
    float* va   = (float*)(W0 + 491520);
    float* cva  = va + 1024;
    float* sey  = cva + 512;
    float* sesc = sey + 512;

    const dim3 gc16(64, 8);    // TH=16 convs
    const dim3 gc8(128, 8);    // TH=8 (1x1) convs

    // ---- prep ----
    mean_hw_kernel<<<1024, 256, 0, stream>>>(x1, va);
    convva_kernel<<<1, 512, 0, stream>>>(va, conv_w, cva);
    repack_x1_kernel<<<dim3(256, 8), 256, 0, stream>>>(x1, x1a, x1b);
    prep_w_kernel<<<32, 256, 0, stream>>>(conv_w,   Wp1, 64, 128, 1, 192, 0);
    prep_w_kernel<<<32, 256, 0, stream>>>(conv1_w,  Wp1, 64, 128, 1, 192, 64);
    prep_w_kernel<<<32, 256, 0, stream>>>(conv2_w,  Wp1, 64, 128, 1, 192, 128);
    prep_w_kernel<<<144, 256, 0, stream>>>(c0_w,    Wc0,   64, 64, 3, 64, 0);
    prep_w_kernel<<<144, 256, 0, stream>>>(attc_w,  Wattc, 64, 64, 3, 64, 0);
    prep_w_kernel<<<400, 256, 0, stream>>>(c05_w,   Wc05,  64, 64, 5, 64, 0);
    prep_w_kernel<<<32, 256, 0, stream>>>(conv0a_w, Wc0a,  64, 128, 1, 64, 0);
    prep_w_kernel<<<144, 256, 0, stream>>>(conv0b_w, Wc0b, 64, 64, 3, 64, 0);

    // ---- 1x1 triple over x1 ----
    conv_mfma<1, 128, 8><<<gc8, 256, 0, stream>>>(x1a, x1b, Wp1, 192, 0,
        conv1_g, conv1_b, kk, cva, conv_bias, A1, A2_bf, f2, att0, fuse_bf, nullptr, 3);
    conv_mfma<1, 128, 8><<<gc8, 256, 0, stream>>>(x1a, x1b, Wp1, 192, 64,
        conv1_g, conv1_b, kk, cva, conv_bias, A1, A2_bf, f2, nullptr, f1_bf, nullptr, 0);
    conv_mfma<1, 128, 8><<<gc8, 256, 0, stream>>>(x1a, x1b, Wp1, 192, 128,
        conv2_g, conv2_b, kk, cva, conv_bias, A1, A2_bf, nullptr, f2, nullptr, nullptr, 0);

    mean_hw_kernel<<<512, 256, 0, stream>>>(att0, sey);
    se_mlp_kernel<<<1, 512, 0, stream>>>(sey, se_w1, se_w2, sesc);

    // ---- 3x3 chain ----
    conv_mfma<3, 64, 16><<<gc16, 256, 0, stream>>>(fuse_bf, nullptr, Wc0, 64, 0,
        c0_g, c0_b, kk, cva, conv_bias, A1, A2_bf, f2, nullptr, eadd_bf, nullptr, 0);
    conv_mfma<3, 64, 16><<<gc16, 256, 0, stream>>>(eadd_bf, nullptr, Wattc, 64, 0,
        attc_g, attc_b, kk, cva, conv_bias, A1, A2_bf, f2, A1, nullptr, nullptr, 1);
    conv_mfma<3, 64, 16><<<gc16, 256, 0, stream>>>(f1_bf, nullptr, Wc0, 64, 0,
        c0_g, c0_b, kk, cva, conv_bias, A1, A2_bf, f2, nullptr, out1_bf, nullptr, 2);
    conv_mfma<3, 64, 16><<<gc16, 256, 0, stream>>>(out1_bf, nullptr, Wattc, 64, 0,
        attc_g, attc_b, kk, cva, conv_bias, A1, A2_bf, f2, nullptr, A2_bf, nullptr, 1);

    // ---- dyndil + 5x5 chain (mul3/add3 fused into epilogues) ----
    dyndil_kernel<<<2048, 256, 0, stream>>>(f2, kk, out2_bf);
    conv_mfma<5, 64, 16><<<gc16, 256, 0, stream>>>(out2_bf, nullptr, Wc05, 64, 0,
        c05_g, c05_b, kk, cva, conv_bias, A1, A2_bf, f2, nullptr, oc_bf, fuseout2_bf, 4);
    conv_mfma<5, 64, 16><<<gc16, 256, 0, stream>>>(fuseout2_bf, nullptr, Wc05, 64, 0,
        c05_g, c05_b, kk, cva, conv_bias, A1, oc_bf, f2, nullptr, eout2_bf, nullptr, 5);
    conv_mfma<5, 64, 16><<<gc16, 256, 0, stream>>>(eout2_bf, nullptr, Wc05, 64, 0,
        c05_g, c05_b, kk, cva, conv_bias, A1, A2_bf, f2, nullptr, out2fin_bf, nullptr, 0);

    // ---- head ----
    conv_mfma<1, 128, 8><<<gc8, 256, 0, stream>>>(out1_bf, out2fin_bf, Wc0a, 64, 0,
        conv0a_g, conv0a_b, kk, cva, conv_bias, A1, A2_bf, f2, nullptr, outa_bf, nullptr, 0);
    conv_mfma<3, 64, 16><<<gc16, 256, 0, stream>>>(outa_bf, nullptr, Wc0b, 64, 0,
        conv0b_g, conv0b_b, kk, cva, conv_bias, A1, A2_bf, f2, outb, nullptr, nullptr, 0);
    final_kernel<<<8192, 256, 0, stream>>>(att0, sesc, outb, A1, (float*)d_out);
}